// Round 2
// baseline (332.446 us; speedup 1.0000x reference)
//
#include <hip/hip_runtime.h>
#include <math.h>

// EGCL_Multi on MFMA. R18 (resubmit; prior bench was an infra failure):
// k_edge re-tiled from 8 waves x (16x128) to 4 waves x (64x64) output
// tiles -> LDS ds_read traffic per FLOP halves (9KB/8MFMA -> 8KB/16MFMA
// per kt). MFMA operands swapped (weights as A, acts as B; identical frag
// layout on both slots) so D is edge-major: per-lane 4-consecutive
// channels -> cvt_pk_bf16 + ds_write_b64 epilogues, dwordx4 P/Q/bias
// loads. N=512, NH=8, HD=128, M=256.
#define N_NODES 512
#define NH 8
#define HD 128
#define M 256
#define PITCH 264        // LDS activation row pitch in bf16 (528B)
#define JTILE 64         // edges (j) per block

typedef __bf16 v8bf __attribute__((ext_vector_type(8)));
typedef float f32x4 __attribute__((ext_vector_type(4)));
typedef unsigned uint2v __attribute__((ext_vector_type(2)));

__device__ __forceinline__ float silu_f(float v) {
  return v * __builtin_amdgcn_rcpf(1.f + __expf(-v));
}
__device__ __forceinline__ float sigmoid_f(float v) {
  return __builtin_amdgcn_rcpf(1.f + __expf(-v));
}
// RNE (weight prep / sqn only)
__device__ __forceinline__ unsigned short f2bf(float f) {
  unsigned u = __float_as_uint(f);
  u += 0x7fffu + ((u >> 16) & 1u);
  return (unsigned short)(u >> 16);
}
__device__ __forceinline__ float bf2f(unsigned short s) {
  return __uint_as_float(((unsigned)s) << 16);
}
// pack 2 f32 -> 2 bf16 in one instruction (low = lo, high = hi)
__device__ __forceinline__ unsigned cvt_pk_bf16(float lo, float hi) {
  unsigned r;
  asm("v_cvt_pk_bf16_f32 %0, %1, %2" : "=v"(r) : "v"(lo), "v"(hi));
  return r;
}

// async global->LDS, 16B/lane; LDS dest = wave-uniform base + lane*16.
__device__ __forceinline__ void gl2lds16(const unsigned short* g, unsigned short* l) {
  __builtin_amdgcn_global_load_lds(
      (const __attribute__((address_space(1))) unsigned int*)g,
      (__attribute__((address_space(3))) unsigned int*)l, 16, 0, 0);
}

// ---------------------------------------------------------------------------
// Fused prep (blocks 0..815, COALESCED source reads) + P/Q & zeroing (816..).
// Frag layout: frag[((kt*16+nt)*64+lane)*8+j] = W[kt*32+(lane>>4)*8+j][nt*16+(lane&15)]
// We1 @0, Wx0 @65536, Wx1 @131072, Wxo(256x8 pad16) @196608,
// We0[0:8] (K=8 pad 32, 16 nt tiles) @200704 (8192 shorts).
// ---------------------------------------------------------------------------
__global__ __launch_bounds__(256) void k_pre(
    const float* __restrict__ x, const float* __restrict__ h,
    const float* __restrict__ We0, const float* __restrict__ be0,
    const float* __restrict__ We1, const float* __restrict__ Wx0,
    const float* __restrict__ Wx1, const float* __restrict__ Wxo,
    unsigned short* __restrict__ wsB,
    float* __restrict__ P, float* __restrict__ Q,
    float* __restrict__ mi, float* __restrict__ shift)
{
  const int t = threadIdx.x;
  if (blockIdx.x < 816) {
    const int gid = blockIdx.x * 256 + t;
    if (gid >= 208896) return;
    float val;
    int dst;
    if (gid < 196608) {                      // We1/Wx0/Wx1: e = k*256+n (coalesced)
      const int layer = gid >> 16, e = gid & 65535;
      const int k = e >> 8, n = e & 255;
      const float* W = (layer == 0) ? We1 : (layer == 1) ? Wx0 : Wx1;
      val = W[e];
      const int kt = k >> 5, w = k & 31, quad = w >> 3, j = w & 7;
      const int nt = n >> 4, lnib = n & 15;
      dst = layer * 65536 + ((kt * 16 + nt) * 64 + quad * 16 + lnib) * 8 + j;
    } else if (gid < 198656) {               // Wxo valid: e = k*8+col (coalesced)
      const int e = gid - 196608;
      val = Wxo[e];
      const int k = e >> 3, col = e & 7;
      const int kt = k >> 5, w = k & 31, quad = w >> 3, j = w & 7;
      dst = 196608 + (kt * 64 + quad * 16 + col) * 8 + j;
    } else if (gid < 200704) {               // Wxo pad (cols 8..15) = 0
      const int e = gid - 198656;
      val = 0.f;
      const int k = e >> 3, col = e & 7;
      const int kt = k >> 5, w = k & 31, quad = w >> 3, j = w & 7;
      dst = 196608 + (kt * 64 + quad * 16 + col + 8) * 8 + j;
    } else if (gid < 202752) {               // We0[0:8] valid: e = j*256+n (coalesced)
      const int e = gid - 200704;
      val = We0[e];
      const int j = e >> 8, n = e & 255, nt = n >> 4, lnib = n & 15;
      dst = 200704 + (nt * 64 + lnib) * 8 + j;              // quad 0
    } else {                                 // We0 frag zero rows (quads 1..3)
      const int e = gid - 202752;
      val = 0.f;
      const int q = 1 + (e >> 11), rem = e & 2047;
      const int j = rem & 7, lnib = (rem >> 3) & 15, nt = rem >> 7;
      dst = 200704 + (nt * 64 + q * 16 + lnib) * 8 + j;
    }
    wsB[dst] = f2bf(val);
    return;
  }
  // ---- P/Q branch ----
  const int i = blockIdx.x - 816;
  __shared__ float s_x[24];
  __shared__ float s_hc[192];
  mi[i * M + t] = 0.f;                       // zeroing replaces memset
  if (t < 24) { shift[i * 24 + t] = 0.f; s_x[t] = x[i * 24 + t]; }
  __syncthreads();
  if (t < HD) {
    s_hc[t] = h[i * HD + t];
  } else if (t < 192) {
    const int p = t - HD, a = p >> 3, b = p & 7;
    float s = 0.f;
#pragma unroll
    for (int d = 0; d < 3; ++d) {
      const float dx = s_x[a * 3 + d] - s_x[b * 3 + d];
      s = fmaf(dx, dx, s);
    }
    s_hc[t] = s;
  }
  __syncthreads();
  float p = 0.f, q = 0.f;
  for (int k = 0; k < 192; ++k) {
    const float hv = s_hc[k];
    p = fmaf(hv, We0[(8 + k) * M + t], p);
    q = fmaf(hv, We0[(200 + k) * M + t], q);
  }
  P[i * M + t] = p;
  Q[i * M + t] = q + be0[t];                 // be0 folded
}

// ---------------------------------------------------------------------------
// Fused edge pipeline. Block = (i, 64-j tile), 256 threads = 4 waves.
// Wave wq owns chans [64*wq, 64*wq+64) for ALL 64 edges (64x64 tile).
// MFMA operands swapped: D[chan][edge]; acc[ct][et][reg]:
//   chan = cb + ct*16 + quad*4 + reg, edge = et*16 + lnib.
// B double-buffered: stage kt+1 while MFMAing kt; 1 barrier per kt.
// ---------------------------------------------------------------------------
__global__ __launch_bounds__(256, 2) void k_edge(
    const float* __restrict__ x,
    const float* __restrict__ P, const float* __restrict__ Q,
    const float* __restrict__ be1,
    const float* __restrict__ Winf, const float* __restrict__ binf,
    const float* __restrict__ bx0, const float* __restrict__ bx1,
    const float* __restrict__ bxo,
    const unsigned short* __restrict__ wsB,
    float* __restrict__ mi_acc, float* __restrict__ shift_acc)
{
  const int i  = blockIdx.x;
  const int j0 = blockIdx.y * JTILE;
  const int t  = threadIdx.x;
  const int lane = t & 63, wq = t >> 6;
  const int lnib = lane & 15, quad = lane >> 4;
  const int cb = wq * 64;

  __shared__ __align__(16) unsigned short a_act[JTILE * PITCH];   // 33 KB
  __shared__ __align__(16) unsigned short B_buf[2][8192];         // 32 KB (dbuf)
  __shared__ __align__(16) float s_sqn[JTILE][8];                 // 2 KB
  __shared__ __align__(16) unsigned short s_sqnb[JTILE][8];       // 1 KB
  __shared__ float s_red[JTILE][4];                               // 1 KB
  __shared__ float s_e[JTILE];                                    // 256 B

  // one kt slice of B: each wave stages 2048 shorts (4KB)
  auto stage = [&](const unsigned short* __restrict__ Bg, int kt, int which) {
    const unsigned short* src = Bg + kt * 8192 + wq * 2048 + lane * 8;
    unsigned short* dst = &B_buf[which][wq * 2048];   // wave-uniform base
    gl2lds16(src,        dst);
    gl2lds16(src + 512,  dst + 512);
    gl2lds16(src + 1024, dst + 1024);
    gl2lds16(src + 1536, dst + 1536);
  };

  // ---- sqn for all 64 edges (read cross-wave -> barrier below) ----
#pragma unroll
  for (int kk = 0; kk < 2; ++kk) {
    const int idx = kk * 256 + t;
    const int r = idx >> 3, hh = idx & 7;
    const int j = j0 + r;
    float s = 0.f;
#pragma unroll
    for (int d = 0; d < 3; ++d) {
      const float dx = x[j * 24 + hh * 3 + d] - x[i * 24 + hh * 3 + d];
      s = fmaf(dx, dx, s);
    }
    s_sqn[r][hh] = s;
    s_sqnb[r][hh] = f2bf(s);
  }

  stage(wsB, 0, 0);            // prefetch GEMM1 kt0 into buf0
  const float binf0 = binf[0];
  __syncthreads();             // s_sqnb visible + kt0 staging drained

  f32x4 acc[4][4];             // [ct][et] -> AGPR/VGPR (64 f32)

  // ---- stage 0: acc = P[j] + sqn @ We0[0:8]; epilogue += Q[i], silu ----
  {
#pragma unroll
    for (int ct = 0; ct < 4; ++ct)
#pragma unroll
      for (int et = 0; et < 4; ++et)
        acc[ct][et] = *(const f32x4*)&P[(j0 + et * 16 + lnib) * M + cb + ct * 16 + quad * 4];
    const unsigned short* W0 = wsB + 200704;
    v8bf wf[4], af[4];
#pragma unroll
    for (int ct = 0; ct < 4; ++ct)
      wf[ct] = *(const v8bf*)&W0[((wq * 4 + ct) * 64 + lane) * 8];
#pragma unroll
    for (int et = 0; et < 4; ++et)
      af[et] = *(const v8bf*)&s_sqnb[et * 16 + lnib][0];   // k>=8 garbage, W rows zero
#pragma unroll
    for (int ct = 0; ct < 4; ++ct)
#pragma unroll
      for (int et = 0; et < 4; ++et)
        acc[ct][et] = __builtin_amdgcn_mfma_f32_16x16x32_bf16(wf[ct], af[et], acc[ct][et], 0, 0, 0);
#pragma unroll
    for (int ct = 0; ct < 4; ++ct) {
      const f32x4 qv = *(const f32x4*)&Q[i * M + cb + ct * 16 + quad * 4];
#pragma unroll
      for (int et = 0; et < 4; ++et) {
        const int row = et * 16 + lnib;
        const unsigned w0 = cvt_pk_bf16(silu_f(acc[ct][et][0] + qv[0]),
                                        silu_f(acc[ct][et][1] + qv[1]));
        const unsigned w1 = cvt_pk_bf16(silu_f(acc[ct][et][2] + qv[2]),
                                        silu_f(acc[ct][et][3] + qv[3]));
        *(uint2v*)&a_act[row * PITCH + cb + ct * 16 + quad * 4] = (uint2v){w0, w1};
      }
    }
  }

  // 64x64 GEMM per wave, dbuf pipeline. Precondition: Bg kt0 staged in buf0
  // and drained. Postcondition (if Bnext): Bnext kt0 staged into buf0 + drained.
  auto run_gemm = [&](const unsigned short* __restrict__ Bg,
                      const unsigned short* __restrict__ Bnext) {
    __syncthreads();   // prior epilogue visible + pending staging drained
#pragma unroll
    for (int kt = 0; kt < 8; ++kt) {
      if (kt < 7)      stage(Bg, kt + 1, (kt + 1) & 1);
      else if (Bnext)  stage(Bnext, 0, 0);
      v8bf wf[4], af[4];
#pragma unroll
      for (int ct = 0; ct < 4; ++ct)
        wf[ct] = *(const v8bf*)&B_buf[kt & 1][(wq * 4 + ct) * 512 + lane * 8];
#pragma unroll
      for (int et = 0; et < 4; ++et)
        af[et] = *(const v8bf*)&a_act[(et * 16 + lnib) * PITCH + kt * 32 + quad * 8];
#pragma unroll
      for (int ct = 0; ct < 4; ++ct)
#pragma unroll
        for (int et = 0; et < 4; ++et)
          acc[ct][et] = __builtin_amdgcn_mfma_f32_16x16x32_bf16(wf[ct], af[et], acc[ct][et], 0, 0, 0);
      __syncthreads(); // reads of buf[kt&1] done; staging issued above drained
    }
  };

  // ===== GEMM1: m = silu(a1 @ We1 + be1), diag mask, gate =====
#pragma unroll
  for (int ct = 0; ct < 4; ++ct) {
    const f32x4 b = *(const f32x4*)&be1[cb + ct * 16 + quad * 4];
#pragma unroll
    for (int et = 0; et < 4; ++et) acc[ct][et] = b;
  }
  run_gemm(wsB, wsB + 65536);
  {
    float ge[4] = {0.f, 0.f, 0.f, 0.f};
#pragma unroll
    for (int ct = 0; ct < 4; ++ct) {
      const f32x4 wv = *(const f32x4*)&Winf[cb + ct * 16 + quad * 4];
#pragma unroll
      for (int et = 0; et < 4; ++et) {
        const int row = et * 16 + lnib;
        const bool dz = (j0 + row == i);
        const float v0 = dz ? 0.f : silu_f(acc[ct][et][0]);
        const float v1 = dz ? 0.f : silu_f(acc[ct][et][1]);
        const float v2 = dz ? 0.f : silu_f(acc[ct][et][2]);
        const float v3 = dz ? 0.f : silu_f(acc[ct][et][3]);
        ge[et] = fmaf(v0, wv[0], ge[et]);
        ge[et] = fmaf(v1, wv[1], ge[et]);
        ge[et] = fmaf(v2, wv[2], ge[et]);
        ge[et] = fmaf(v3, wv[3], ge[et]);
        *(uint2v*)&a_act[row * PITCH + cb + ct * 16 + quad * 4] =
            (uint2v){cvt_pk_bf16(v0, v1), cvt_pk_bf16(v2, v3)};
      }
    }
#pragma unroll
    for (int et = 0; et < 4; ++et) {
      float g = ge[et];
      g += __shfl_xor(g, 16);
      g += __shfl_xor(g, 32);
      if (quad == 0) s_red[et * 16 + lnib][wq] = g;   // per-wave chan-quarter partial
    }
  }
  __syncthreads();                           // m writes + gate partials visible
  if (t < JTILE)
    s_e[t] = sigmoid_f(s_red[t][0] + s_red[t][1] + s_red[t][2] + s_red[t][3] + binf0);
  __syncthreads();

  // ===== mi: wave wq re-reads rows [16wq,16wq+16), 4 chans/lane =====
  {
    const int r0 = wq * 16;
    float m0 = 0.f, m1 = 0.f, m2 = 0.f, m3 = 0.f;
#pragma unroll
    for (int r = 0; r < 16; ++r) {
      const float ev = s_e[r0 + r];
      const unsigned pa = *(const unsigned*)&a_act[(r0 + r) * PITCH + lane * 2];
      const unsigned pb = *(const unsigned*)&a_act[(r0 + r) * PITCH + 128 + lane * 2];
      m0 = fmaf(bf2f((unsigned short)(pa & 0xffffu)), ev, m0);
      m1 = fmaf(bf2f((unsigned short)(pa >> 16)), ev, m1);
      m2 = fmaf(bf2f((unsigned short)(pb & 0xffffu)), ev, m2);
      m3 = fmaf(bf2f((unsigned short)(pb >> 16)), ev, m3);
    }
    atomicAdd(&mi_acc[i * M + lane * 2 + 0], m0);
    atomicAdd(&mi_acc[i * M + lane * 2 + 1], m1);
    atomicAdd(&mi_acc[i * M + 128 + lane * 2 + 0], m2);
    atomicAdd(&mi_acc[i * M + 128 + lane * 2 + 1], m3);
  }

  // ===== GEMM2: a2 = silu(m @ Wx0 + bx0) =====
#pragma unroll
  for (int ct = 0; ct < 4; ++ct) {
    const f32x4 b = *(const f32x4*)&bx0[cb + ct * 16 + quad * 4];
#pragma unroll
    for (int et = 0; et < 4; ++et) acc[ct][et] = b;
  }
  run_gemm(wsB + 65536, wsB + 131072);
#pragma unroll
  for (int ct = 0; ct < 4; ++ct)
#pragma unroll
    for (int et = 0; et < 4; ++et) {
      const int row = et * 16 + lnib;
      const unsigned w0 = cvt_pk_bf16(silu_f(acc[ct][et][0]), silu_f(acc[ct][et][1]));
      const unsigned w1 = cvt_pk_bf16(silu_f(acc[ct][et][2]), silu_f(acc[ct][et][3]));
      *(uint2v*)&a_act[row * PITCH + cb + ct * 16 + quad * 4] = (uint2v){w0, w1};
    }

  // ===== GEMM3: a3 = silu(a2 @ Wx1 + bx1) =====
#pragma unroll
  for (int ct = 0; ct < 4; ++ct) {
    const f32x4 b = *(const f32x4*)&bx1[cb + ct * 16 + quad * 4];
#pragma unroll
    for (int et = 0; et < 4; ++et) acc[ct][et] = b;
  }
  run_gemm(wsB + 131072, nullptr);
#pragma unroll
  for (int ct = 0; ct < 4; ++ct)
#pragma unroll
    for (int et = 0; et < 4; ++et) {
      const int row = et * 16 + lnib;
      const unsigned w0 = cvt_pk_bf16(silu_f(acc[ct][et][0]), silu_f(acc[ct][et][1]));
      const unsigned w1 = cvt_pk_bf16(silu_f(acc[ct][et][2]), silu_f(acc[ct][et][3]));
      *(uint2v*)&a_act[row * PITCH + cb + ct * 16 + quad * 4] = (uint2v){w0, w1};
    }
  __syncthreads();                           // a3 complete (GEMM4 reads all cols)

  // ===== GEMM4 + shift: wave wq handles edges [16wq,16wq+16), full K =====
  {
    const int e0 = wq * 16;
    f32x4 px;
    if (quad < 2) px = *(const f32x4*)&bxo[quad * 4];     // oc = quad*4+reg (valid <8)
    else          px = (f32x4){0.f, 0.f, 0.f, 0.f};       // padded zero rows
    const unsigned short* Bx = wsB + 196608;
#pragma unroll
    for (int kt = 0; kt < 8; ++kt) {
      const v8bf af = *(const v8bf*)&a_act[(e0 + lnib) * PITCH + kt * 32 + quad * 8];
      const v8bf wf = *(const v8bf*)&Bx[(kt * 64 + lane) * 8];
      px = __builtin_amdgcn_mfma_f32_16x16x32_bf16(wf, af, px, 0, 0, 0);
    }
    const int jg = j0 + e0 + lnib;
    float c0[4], c1[4], c2[4];
#pragma unroll
    for (int r = 0; r < 4; ++r) { c0[r] = 0.f; c1[r] = 0.f; c2[r] = 0.f; }
    if (quad < 2 && jg != i) {
#pragma unroll
      for (int r = 0; r < 4; ++r) {
        const int hh = quad * 4 + r;
        const float sq = s_sqn[e0 + lnib][hh];
        const float f  = px[r] * __builtin_amdgcn_rcpf(sqrtf(sq + 1e-8f) + 1.f);
        c0[r] = (x[jg * 24 + hh * 3 + 0] - x[i * 24 + hh * 3 + 0]) * f;
        c1[r] = (x[jg * 24 + hh * 3 + 1] - x[i * 24 + hh * 3 + 1]) * f;
        c2[r] = (x[jg * 24 + hh * 3 + 2] - x[i * 24 + hh * 3 + 2]) * f;
      }
    }
#pragma unroll
    for (int r = 0; r < 4; ++r) {
#pragma unroll
      for (int s = 1; s <= 8; s <<= 1) {
        c0[r] += __shfl_xor(c0[r], s);
        c1[r] += __shfl_xor(c1[r], s);
        c2[r] += __shfl_xor(c2[r], s);
      }
    }
    if (lnib == 0 && quad < 2) {
#pragma unroll
      for (int r = 0; r < 4; ++r) {
        const int hh = quad * 4 + r;
        atomicAdd(&shift_acc[i * 24 + hh * 3 + 0], c0[r]);
        atomicAdd(&shift_acc[i * 24 + hh * 3 + 1], c1[r]);
        atomicAdd(&shift_acc[i * 24 + hh * 3 + 2], c2[r]);
      }
    }
  }
}

// ---------------------------------------------------------------------------
// h-output (phi_h MLP + residual) with x-output folded in (threads t<24).
// ---------------------------------------------------------------------------
__global__ __launch_bounds__(256) void k_hout(
    const float* __restrict__ x, const float* __restrict__ shift,
    const float* __restrict__ h, const float* __restrict__ mi,
    const float* __restrict__ Wh0, const float* __restrict__ bh0,
    const float* __restrict__ Wh1, const float* __restrict__ bh1,
    const float* __restrict__ Who, const float* __restrict__ bho,
    float* __restrict__ out_x, float* __restrict__ out_h)
{
  const int i = blockIdx.x, t = threadIdx.x;
  __shared__ float s_in[M + HD];
  __shared__ float s_b[M];
  if (t < 24) out_x[i * 24 + t] = x[i * 24 + t] + shift[i * 24 + t] * (1.f / 511.f);
  s_in[t] = mi[i * M + t];
  if (t < HD) s_in[M + t] = h[i * HD + t];
  __syncthreads();
  float acc = bh0[t];
  for (int k = 0; k < M + HD; ++k) acc = fmaf(s_in[k], Wh0[k * M + t], acc);
  s_b[t] = silu_f(acc);
  __syncthreads();
  float acc2 = bh1[t];
  for (int k = 0; k < M; ++k) acc2 = fmaf(s_b[k], Wh1[k * M + t], acc2);
  const float a1v = silu_f(acc2);
  __syncthreads();
  s_in[t] = a1v;
  __syncthreads();
  if (t < HD) {
    float o = bho[t];
    for (int k = 0; k < M; ++k) o = fmaf(s_in[k], Who[k * HD + t], o);
    out_h[i * HD + t] = h[i * HD + t] + o;
  }
}

// ---------------------------------------------------------------------------
extern "C" void kernel_launch(void* const* d_in, const int* in_sizes, int n_in,
                              void* d_out, int out_size, void* d_ws, size_t ws_size,
                              hipStream_t stream)
{
  const float* x    = (const float*)d_in[0];
  const float* h    = (const float*)d_in[1];
  const float* We0  = (const float*)d_in[2];
  const float* be0  = (const float*)d_in[3];
  const float* We1  = (const float*)d_in[4];
  const float* be1  = (const float*)d_in[5];
  const float* Winf = (const float*)d_in[6];
  const float* binf = (const float*)d_in[7];
  const float* Wx0  = (const float*)d_in[8];
  const float* bx0  = (const float*)d_in[9];
  const float* Wx1  = (const float*)d_in[10];
  const float* bx1  = (const float*)d_in[11];
  const float* Wxo  = (const float*)d_in[12];
  const float* bxo  = (const float*)d_in[13];
  const float* Wh0  = (const float*)d_in[14];
  const float* bh0  = (const float*)d_in[15];
  const float* Wh1  = (const float*)d_in[16];
  const float* bh1  = (const float*)d_in[17];
  const float* Who  = (const float*)d_in[18];
  const float* bho  = (const float*)d_in[19];

  float* out_x = (float*)d_out;                 // [512,8,3]
  float* out_h = out_x + N_NODES * NH * 3;      // [512,128]

  // ws layout (float units): mi[131072] | shift[12288] | P[131072] | Q[131072] | wsB(bf16)
  float* ws    = (float*)d_ws;
  float* mi    = ws;
  float* shift = ws + 131072;
  float* P     = ws + 143360;
  float* Q     = ws + 274432;
  unsigned short* wsB = (unsigned short*)(ws + 405504);

  k_pre<<<816 + N_NODES, 256, 0, stream>>>(
      x, h, We0, be0, We1, Wx0, Wx1, Wxo, wsB, P, Q, mi, shift);
  k_edge<<<dim3(N_NODES, N_NODES / JTILE), 256, 0, stream>>>(
      x, P, Q, be1, Winf, binf, bx0, bx1, bxo, wsB, mi, shift);
  k_hout<<<N_NODES, 256, 0, stream>>>(
      x, shift, h, mi, Wh0, bh0, Wh1, bh1, Who, bho, out_x, out_h);
}

// Round 3
// 285.043 us; speedup vs baseline: 1.1663x; 1.1663x over previous
//
#include <hip/hip_runtime.h>
#include <math.h>

// EGCL_Multi on MFMA. R19: barrier-free inner GEMMs.
// - B (weights) loaded straight from global wsB frags into VGPRs (lane-linear
//   16B/lane coalesced) -> no B LDS, no per-kt barrier, compiler pipelines.
// - a_act stored in MFMA-frag order (32 tiles of 1KB): af ds_read_b128 and
//   epilogue ds_write_b64 both lane-linear conflict-free.
// - mi computed from kept packed-bf16 registers (shfl reduce over lnib).
// - 8 barriers/block (was 24), LDS 37KB (was 71KB), 3 blocks/CU target.
// N=512, NH=8, HD=128, M=256.
#define N_NODES 512
#define NH 8
#define HD 128
#define M 256
#define JTILE 64         // edges (j) per block

typedef __bf16 v8bf __attribute__((ext_vector_type(8)));
typedef float f32x4 __attribute__((ext_vector_type(4)));
typedef unsigned uint2v __attribute__((ext_vector_type(2)));

__device__ __forceinline__ float silu_f(float v) {
  return v * __builtin_amdgcn_rcpf(1.f + __expf(-v));
}
__device__ __forceinline__ float sigmoid_f(float v) {
  return __builtin_amdgcn_rcpf(1.f + __expf(-v));
}
// RNE (weight prep / sqn only)
__device__ __forceinline__ unsigned short f2bf(float f) {
  unsigned u = __float_as_uint(f);
  u += 0x7fffu + ((u >> 16) & 1u);
  return (unsigned short)(u >> 16);
}
__device__ __forceinline__ float bf2f_lo(unsigned u) {
  return __uint_as_float(u << 16);
}
__device__ __forceinline__ float bf2f_hi(unsigned u) {
  return __uint_as_float(u & 0xffff0000u);
}
// pack 2 f32 -> 2 bf16 in one instruction (low = lo, high = hi)
__device__ __forceinline__ unsigned cvt_pk_bf16(float lo, float hi) {
  unsigned r;
  asm("v_cvt_pk_bf16_f32 %0, %1, %2" : "=v"(r) : "v"(lo), "v"(hi));
  return r;
}

// ---------------------------------------------------------------------------
// Fused prep (blocks 0..815, COALESCED source reads) + P/Q & zeroing (816..).
// Frag layout: frag[((kt*16+nt)*64+lane)*8+j] = W[kt*32+(lane>>4)*8+j][nt*16+(lane&15)]
// We1 @0, Wx0 @65536, Wx1 @131072, Wxo(256x8 pad16) @196608,
// We0[0:8] (K=8 pad 32, 16 nt tiles) @200704 (8192 shorts).
// ---------------------------------------------------------------------------
__global__ __launch_bounds__(256) void k_pre(
    const float* __restrict__ x, const float* __restrict__ h,
    const float* __restrict__ We0, const float* __restrict__ be0,
    const float* __restrict__ We1, const float* __restrict__ Wx0,
    const float* __restrict__ Wx1, const float* __restrict__ Wxo,
    unsigned short* __restrict__ wsB,
    float* __restrict__ P, float* __restrict__ Q,
    float* __restrict__ mi, float* __restrict__ shift)
{
  const int t = threadIdx.x;
  if (blockIdx.x < 816) {
    const int gid = blockIdx.x * 256 + t;
    if (gid >= 208896) return;
    float val;
    int dst;
    if (gid < 196608) {                      // We1/Wx0/Wx1: e = k*256+n (coalesced)
      const int layer = gid >> 16, e = gid & 65535;
      const int k = e >> 8, n = e & 255;
      const float* W = (layer == 0) ? We1 : (layer == 1) ? Wx0 : Wx1;
      val = W[e];
      const int kt = k >> 5, w = k & 31, quad = w >> 3, j = w & 7;
      const int nt = n >> 4, lnib = n & 15;
      dst = layer * 65536 + ((kt * 16 + nt) * 64 + quad * 16 + lnib) * 8 + j;
    } else if (gid < 198656) {               // Wxo valid: e = k*8+col (coalesced)
      const int e = gid - 196608;
      val = Wxo[e];
      const int k = e >> 3, col = e & 7;
      const int kt = k >> 5, w = k & 31, quad = w >> 3, j = w & 7;
      dst = 196608 + (kt * 64 + quad * 16 + col) * 8 + j;
    } else if (gid < 200704) {               // Wxo pad (cols 8..15) = 0
      const int e = gid - 198656;
      val = 0.f;
      const int k = e >> 3, col = e & 7;
      const int kt = k >> 5, w = k & 31, quad = w >> 3, j = w & 7;
      dst = 196608 + (kt * 64 + quad * 16 + col + 8) * 8 + j;
    } else if (gid < 202752) {               // We0[0:8] valid: e = j*256+n (coalesced)
      const int e = gid - 200704;
      val = We0[e];
      const int j = e >> 8, n = e & 255, nt = n >> 4, lnib = n & 15;
      dst = 200704 + (nt * 64 + lnib) * 8 + j;              // quad 0
    } else {                                 // We0 frag zero rows (quads 1..3)
      const int e = gid - 202752;
      val = 0.f;
      const int q = 1 + (e >> 11), rem = e & 2047;
      const int j = rem & 7, lnib = (rem >> 3) & 15, nt = rem >> 7;
      dst = 200704 + (nt * 64 + q * 16 + lnib) * 8 + j;
    }
    wsB[dst] = f2bf(val);
    return;
  }
  // ---- P/Q branch ----
  const int i = blockIdx.x - 816;
  __shared__ float s_x[24];
  __shared__ float s_hc[192];
  mi[i * M + t] = 0.f;                       // zeroing replaces memset
  if (t < 24) { shift[i * 24 + t] = 0.f; s_x[t] = x[i * 24 + t]; }
  __syncthreads();
  if (t < HD) {
    s_hc[t] = h[i * HD + t];
  } else if (t < 192) {
    const int p = t - HD, a = p >> 3, b = p & 7;
    float s = 0.f;
#pragma unroll
    for (int d = 0; d < 3; ++d) {
      const float dx = s_x[a * 3 + d] - s_x[b * 3 + d];
      s = fmaf(dx, dx, s);
    }
    s_hc[t] = s;
  }
  __syncthreads();
  float p = 0.f, q = 0.f;
  for (int k = 0; k < 192; ++k) {
    const float hv = s_hc[k];
    p = fmaf(hv, We0[(8 + k) * M + t], p);
    q = fmaf(hv, We0[(200 + k) * M + t], q);
  }
  P[i * M + t] = p;
  Q[i * M + t] = q + be0[t];                 // be0 folded
}

// ---------------------------------------------------------------------------
// Fused edge pipeline. Block = (i, 64-j tile), 256 threads = 4 waves.
// Wave wq owns chans [64*wq, 64*wq+64) for ALL 64 edges (64x64 tile).
// D[chan][edge]; acc[ct][et][reg]: chan = cb+ct*16+quad*4+reg, edge = et*16+lnib.
// a_act is frag-ordered: tile (et,kt) at shorts (et*8+kt)*512, element
// (row=et*16+l15, k=kt*32+q*8+j) at ((et*8+kt)*64 + q*16 + l15)*8 + j.
// B frags read straight from global wsB (lane-linear dwordx4) -> no barriers
// inside GEMM loops.
// ---------------------------------------------------------------------------
__global__ __launch_bounds__(256, 3) void k_edge(
    const float* __restrict__ x,
    const float* __restrict__ P, const float* __restrict__ Q,
    const float* __restrict__ be1,
    const float* __restrict__ Winf, const float* __restrict__ binf,
    const float* __restrict__ bx0, const float* __restrict__ bx1,
    const float* __restrict__ bxo,
    const unsigned short* __restrict__ wsB,
    float* __restrict__ mi_acc, float* __restrict__ shift_acc)
{
  const int i  = blockIdx.x;
  const int j0 = blockIdx.y * JTILE;
  const int t  = threadIdx.x;
  const int lane = t & 63, wq = t >> 6;
  const int lnib = lane & 15, quad = lane >> 4;
  const int cb = wq * 64;

  __shared__ __align__(16) unsigned short a_act[32 * 512];        // 32 KB frag-ordered
  __shared__ __align__(16) float s_sqn[JTILE][8];                 // 2 KB
  __shared__ __align__(16) unsigned short s_sqnb[JTILE][8];       // 1 KB
  __shared__ float s_red[JTILE][4];                               // 1 KB
  __shared__ float s_e[JTILE];                                    // 256 B

  f32x4 acc[4][4];             // 64 f32

  // frag store: lane's 4 regs of acc[ct][et] = 4 consecutive j slots.
  auto store_frag = [&](int ct, int et, unsigned w0, unsigned w1) {
    const int tile = et * 8 + 2 * wq + (ct >> 1);
    const int qp   = (ct & 1) * 2 + (quad >> 1);
    const int sidx = (tile * 64 + qp * 16 + lnib) * 8 + (quad & 1) * 4;
    *(uint2v*)&a_act[sidx] = (uint2v){w0, w1};
  };

  // barrier-free 64x64 GEMM: B frags global (coalesced), A frags LDS (lane-linear)
  auto run_gemm = [&](const unsigned short* __restrict__ Bg) {
#pragma unroll
    for (int kt = 0; kt < 8; ++kt) {
      v8bf wf[4], af[4];
#pragma unroll
      for (int ct = 0; ct < 4; ++ct)
        wf[ct] = *(const v8bf*)&Bg[((kt * 16 + wq * 4 + ct) * 64 + lane) * 8];
#pragma unroll
      for (int et = 0; et < 4; ++et)
        af[et] = *(const v8bf*)&a_act[((et * 8 + kt) * 64 + lane) * 8];
#pragma unroll
      for (int ct = 0; ct < 4; ++ct)
#pragma unroll
        for (int et = 0; et < 4; ++et)
          acc[ct][et] = __builtin_amdgcn_mfma_f32_16x16x32_bf16(wf[ct], af[et], acc[ct][et], 0, 0, 0);
    }
  };

  // ---- sqn for all 64 edges ----
#pragma unroll
  for (int kk = 0; kk < 2; ++kk) {
    const int idx = kk * 256 + t;
    const int r = idx >> 3, hh = idx & 7;
    const int j = j0 + r;
    float s = 0.f;
#pragma unroll
    for (int d = 0; d < 3; ++d) {
      const float dx = x[j * 24 + hh * 3 + d] - x[i * 24 + hh * 3 + d];
      s = fmaf(dx, dx, s);
    }
    s_sqn[r][hh] = s;
    s_sqnb[r][hh] = f2bf(s);
  }
  const float binf0 = binf[0];
  __syncthreads();                           // s_sqnb visible

  // ---- stage 0: acc = P[j] + sqn @ We0[0:8]; epilogue += Q[i], silu ----
  {
#pragma unroll
    for (int ct = 0; ct < 4; ++ct)
#pragma unroll
      for (int et = 0; et < 4; ++et)
        acc[ct][et] = *(const f32x4*)&P[(j0 + et * 16 + lnib) * M + cb + ct * 16 + quad * 4];
    const unsigned short* W0 = wsB + 200704;
    v8bf wf[4], af[4];
#pragma unroll
    for (int ct = 0; ct < 4; ++ct)
      wf[ct] = *(const v8bf*)&W0[((wq * 4 + ct) * 64 + lane) * 8];
#pragma unroll
    for (int et = 0; et < 4; ++et)
      af[et] = *(const v8bf*)&s_sqnb[et * 16 + lnib][0];   // k>=8 garbage, W rows zero
#pragma unroll
    for (int ct = 0; ct < 4; ++ct)
#pragma unroll
      for (int et = 0; et < 4; ++et)
        acc[ct][et] = __builtin_amdgcn_mfma_f32_16x16x32_bf16(wf[ct], af[et], acc[ct][et], 0, 0, 0);
#pragma unroll
    for (int ct = 0; ct < 4; ++ct) {
      const f32x4 qv = *(const f32x4*)&Q[i * M + cb + ct * 16 + quad * 4];
#pragma unroll
      for (int et = 0; et < 4; ++et) {
        const unsigned w0 = cvt_pk_bf16(silu_f(acc[ct][et][0] + qv[0]),
                                        silu_f(acc[ct][et][1] + qv[1]));
        const unsigned w1 = cvt_pk_bf16(silu_f(acc[ct][et][2] + qv[2]),
                                        silu_f(acc[ct][et][3] + qv[3]));
        store_frag(ct, et, w0, w1);
      }
    }
  }

  // ===== GEMM1: m = silu(a1 @ We1 + be1), diag mask, gate =====
#pragma unroll
  for (int ct = 0; ct < 4; ++ct) {
    const f32x4 b = *(const f32x4*)&be1[cb + ct * 16 + quad * 4];
#pragma unroll
    for (int et = 0; et < 4; ++et) acc[ct][et] = b;
  }
  __syncthreads();                           // a1 frags visible
  run_gemm(wsB);
  __syncthreads();                           // all waves done reading a1

  unsigned mw[4][4][2];                      // kept packed m for reg-based mi
  {
    float ge[4] = {0.f, 0.f, 0.f, 0.f};
#pragma unroll
    for (int ct = 0; ct < 4; ++ct) {
      const f32x4 wv = *(const f32x4*)&Winf[cb + ct * 16 + quad * 4];
#pragma unroll
      for (int et = 0; et < 4; ++et) {
        const int row = et * 16 + lnib;
        const bool dz = (j0 + row == i);
        const float v0 = dz ? 0.f : silu_f(acc[ct][et][0]);
        const float v1 = dz ? 0.f : silu_f(acc[ct][et][1]);
        const float v2 = dz ? 0.f : silu_f(acc[ct][et][2]);
        const float v3 = dz ? 0.f : silu_f(acc[ct][et][3]);
        ge[et] = fmaf(v0, wv[0], ge[et]);
        ge[et] = fmaf(v1, wv[1], ge[et]);
        ge[et] = fmaf(v2, wv[2], ge[et]);
        ge[et] = fmaf(v3, wv[3], ge[et]);
        const unsigned w0 = cvt_pk_bf16(v0, v1);
        const unsigned w1 = cvt_pk_bf16(v2, v3);
        mw[ct][et][0] = w0; mw[ct][et][1] = w1;
        store_frag(ct, et, w0, w1);
      }
    }
#pragma unroll
    for (int et = 0; et < 4; ++et) {
      float g = ge[et];
      g += __shfl_xor(g, 16);
      g += __shfl_xor(g, 32);
      if (quad == 0) s_red[et * 16 + lnib][wq] = g;   // per-wave chan-quarter partial
    }
  }
  __syncthreads();                           // m frags + gate partials visible
  if (t < JTILE)
    s_e[t] = sigmoid_f(s_red[t][0] + s_red[t][1] + s_red[t][2] + s_red[t][3] + binf0);
  __syncthreads();                           // s_e visible

  // ===== mi from registers: chan sums, shfl-reduce over lnib =====
  {
    float ev[4];
#pragma unroll
    for (int et = 0; et < 4; ++et) ev[et] = s_e[et * 16 + lnib];
    float s[4][4];
#pragma unroll
    for (int ct = 0; ct < 4; ++ct) {
      s[ct][0] = 0.f; s[ct][1] = 0.f; s[ct][2] = 0.f; s[ct][3] = 0.f;
#pragma unroll
      for (int et = 0; et < 4; ++et) {
        s[ct][0] = fmaf(bf2f_lo(mw[ct][et][0]), ev[et], s[ct][0]);
        s[ct][1] = fmaf(bf2f_hi(mw[ct][et][0]), ev[et], s[ct][1]);
        s[ct][2] = fmaf(bf2f_lo(mw[ct][et][1]), ev[et], s[ct][2]);
        s[ct][3] = fmaf(bf2f_hi(mw[ct][et][1]), ev[et], s[ct][3]);
      }
    }
#pragma unroll
    for (int ct = 0; ct < 4; ++ct)
#pragma unroll
      for (int r = 0; r < 4; ++r) {
        float v = s[ct][r];
        v += __shfl_xor(v, 1);
        v += __shfl_xor(v, 2);
        v += __shfl_xor(v, 4);
        v += __shfl_xor(v, 8);
        s[ct][r] = v;
      }
    if (lnib == 0) {
#pragma unroll
      for (int ct = 0; ct < 4; ++ct)
#pragma unroll
        for (int r = 0; r < 4; ++r)
          atomicAdd(&mi_acc[i * M + cb + ct * 16 + quad * 4 + r], s[ct][r]);
    }
  }

  // ===== GEMM2: a2 = silu(m @ Wx0 + bx0) =====
#pragma unroll
  for (int ct = 0; ct < 4; ++ct) {
    const f32x4 b = *(const f32x4*)&bx0[cb + ct * 16 + quad * 4];
#pragma unroll
    for (int et = 0; et < 4; ++et) acc[ct][et] = b;
  }
  run_gemm(wsB + 65536);                     // m frags visible (2 barriers ago)
  __syncthreads();                           // all waves done reading m
#pragma unroll
  for (int ct = 0; ct < 4; ++ct)
#pragma unroll
    for (int et = 0; et < 4; ++et) {
      const unsigned w0 = cvt_pk_bf16(silu_f(acc[ct][et][0]), silu_f(acc[ct][et][1]));
      const unsigned w1 = cvt_pk_bf16(silu_f(acc[ct][et][2]), silu_f(acc[ct][et][3]));
      store_frag(ct, et, w0, w1);
    }

  // ===== GEMM3: a3 = silu(a2 @ Wx1 + bx1) =====
#pragma unroll
  for (int ct = 0; ct < 4; ++ct) {
    const f32x4 b = *(const f32x4*)&bx1[cb + ct * 16 + quad * 4];
#pragma unroll
    for (int et = 0; et < 4; ++et) acc[ct][et] = b;
  }
  __syncthreads();                           // a2 frags visible
  run_gemm(wsB + 131072);
  __syncthreads();                           // all waves done reading a2
#pragma unroll
  for (int ct = 0; ct < 4; ++ct)
#pragma unroll
    for (int et = 0; et < 4; ++et) {
      const unsigned w0 = cvt_pk_bf16(silu_f(acc[ct][et][0]), silu_f(acc[ct][et][1]));
      const unsigned w1 = cvt_pk_bf16(silu_f(acc[ct][et][2]), silu_f(acc[ct][et][3]));
      store_frag(ct, et, w0, w1);
    }
  __syncthreads();                           // a3 complete (GEMM4 reads all cols)

  // ===== GEMM4 + shift: wave wq handles edges [16wq,16wq+16), full K =====
  {
    f32x4 px;
    if (quad < 2) px = *(const f32x4*)&bxo[quad * 4];     // oc = quad*4+reg (valid <8)
    else          px = (f32x4){0.f, 0.f, 0.f, 0.f};       // padded zero rows
    const unsigned short* Bx = wsB + 196608;
#pragma unroll
    for (int kt = 0; kt < 8; ++kt) {
      const v8bf af = *(const v8bf*)&a_act[((wq * 8 + kt) * 64 + lane) * 8];
      const v8bf wf = *(const v8bf*)&Bx[(kt * 64 + lane) * 8];
      px = __builtin_amdgcn_mfma_f32_16x16x32_bf16(wf, af, px, 0, 0, 0);
    }
    const int e0 = wq * 16;
    const int jg = j0 + e0 + lnib;
    float c0[4], c1[4], c2[4];
#pragma unroll
    for (int r = 0; r < 4; ++r) { c0[r] = 0.f; c1[r] = 0.f; c2[r] = 0.f; }
    if (quad < 2 && jg != i) {
#pragma unroll
      for (int r = 0; r < 4; ++r) {
        const int hh = quad * 4 + r;
        const float sq = s_sqn[e0 + lnib][hh];
        const float f  = px[r] * __builtin_amdgcn_rcpf(sqrtf(sq + 1e-8f) + 1.f);
        c0[r] = (x[jg * 24 + hh * 3 + 0] - x[i * 24 + hh * 3 + 0]) * f;
        c1[r] = (x[jg * 24 + hh * 3 + 1] - x[i * 24 + hh * 3 + 1]) * f;
        c2[r] = (x[jg * 24 + hh * 3 + 2] - x[i * 24 + hh * 3 + 2]) * f;
      }
    }
#pragma unroll
    for (int r = 0; r < 4; ++r) {
#pragma unroll
      for (int s = 1; s <= 8; s <<= 1) {
        c0[r] += __shfl_xor(c0[r], s);
        c1[r] += __shfl_xor(c1[r], s);
        c2[r] += __shfl_xor(c2[r], s);
      }
    }
    if (lnib == 0 && quad < 2) {
#pragma unroll
      for (int r = 0; r < 4; ++r) {
        const int hh = quad * 4 + r;
        atomicAdd(&shift_acc[i * 24 + hh * 3 + 0], c0[r]);
        atomicAdd(&shift_acc[i * 24 + hh * 3 + 1], c1[r]);
        atomicAdd(&shift_acc[i * 24 + hh * 3 + 2], c2[r]);
      }
    }
  }
}

// ---------------------------------------------------------------------------
// h-output (phi_h MLP + residual) with x-output folded in (threads t<24).
// ---------------------------------------------------------------------------
__global__ __launch_bounds__(256) void k_hout(
    const float* __restrict__ x, const float* __restrict__ shift,
    const float* __restrict__ h, const float* __restrict__ mi,
    const float* __restrict__ Wh0, const float* __restrict__ bh0,
    const float* __restrict__ Wh1, const float* __restrict__ bh1,
    const float* __restrict__ Who, const float* __restrict__ bho,
    float* __restrict__ out_x, float* __restrict__ out_h)
{
  const int i = blockIdx.x, t = threadIdx.x;
  __shared__ float s_in[M + HD];
  __shared__ float s_b[M];
  if (t < 24) out_x[i * 24 + t] = x[i * 24 + t] + shift[i * 24 + t] * (1.f / 511.f);
  s_in[t] = mi[i * M + t];
  if (t < HD) s_in[M + t] = h[i * HD + t];
  __syncthreads();
  float acc = bh0[t];
  for (int k = 0; k < M + HD; ++k) acc = fmaf(s_in[k], Wh0[k * M + t], acc);
  s_b[t] = silu_f(acc);
  __syncthreads();
  float acc2 = bh1[t];
  for (int k = 0; k < M; ++k) acc2 = fmaf(s_b[k], Wh1[k * M + t], acc2);
  const float a1v = silu_f(acc2);
  __syncthreads();
  s_in[t] = a1v;
  __syncthreads();
  if (t < HD) {
    float o = bho[t];
    for (int k = 0; k < M; ++k) o = fmaf(s_in[k], Who[k * HD + t], o);
    out_h[i * HD + t] = h[i * HD + t] + o;
  }
}

// ---------------------------------------------------------------------------
extern "C" void kernel_launch(void* const* d_in, const int* in_sizes, int n_in,
                              void* d_out, int out_size, void* d_ws, size_t ws_size,
                              hipStream_t stream)
{
  const float* x    = (const float*)d_in[0];
  const float* h    = (const float*)d_in[1];
  const float* We0  = (const float*)d_in[2];
  const float* be0  = (const float*)d_in[3];
  const float* We1  = (const float*)d_in[4];
  const float* be1  = (const float*)d_in[5];
  const float* Winf = (const float*)d_in[6];
  const float* binf = (const float*)d_in[7];
  const float* Wx0  = (const float*)d_in[8];
  const float* bx0  = (const float*)d_in[9];
  const float* Wx1  = (const float*)d_in[10];
  const float* bx1  = (const float*)d_in[11];
  const float* Wxo  = (const float*)d_in[12];
  const float* bxo  = (const float*)d_in[13];
  const float* Wh0  = (const float*)d_in[14];
  const float* bh0  = (const float*)d_in[15];
  const float* Wh1  = (const float*)d_in[16];
  const float* bh1  = (const float*)d_in[17];
  const float* Who  = (const float*)d_in[18];
  const float* bho  = (const float*)d_in[19];

  float* out_x = (float*)d_out;                 // [512,8,3]
  float* out_h = out_x + N_NODES * NH * 3;      // [512,128]

  // ws layout (float units): mi[131072] | shift[12288] | P[131072] | Q[131072] | wsB(bf16)
  float* ws    = (float*)d_ws;
  float* mi    = ws;
  float* shift = ws + 131072;
  float* P     = ws + 143360;
  float* Q     = ws + 274432;
  unsigned short* wsB = (unsigned short*)(ws + 405504);

  k_pre<<<816 + N_NODES, 256, 0, stream>>>(
      x, h, We0, be0, We1, Wx0, Wx1, Wxo, wsB, P, Q, mi, shift);
  k_edge<<<dim3(N_NODES, N_NODES / JTILE), 256, 0, stream>>>(
      x, P, Q, be1, Winf, binf, bx0, bx1, bxo, wsB, mi, shift);
  k_hout<<<N_NODES, 256, 0, stream>>>(
      x, shift, h, mi, Wh0, bh0, Wh1, bh1, Who, bho, out_x, out_h);
}